// Round 1
// baseline (645.158 us; speedup 1.0000x reference)
//
#include <hip/hip_runtime.h>
#include <math.h>

#define BATCH 2048
#define NCLS 62

__device__ __forceinline__ float wave_max(float v) {
#pragma unroll
    for (int m = 32; m >= 1; m >>= 1) v = fmaxf(v, __shfl_xor(v, m, 64));
    return v;
}
__device__ __forceinline__ float wave_sum(float v) {
#pragma unroll
    for (int m = 32; m >= 1; m >>= 1) v += __shfl_xor(v, m, 64);
    return v;
}

// Kernel A: per-batch confidences + dot products -> norm_conf outputs + scale cache
__global__ __launch_bounds__(256) void head_kernel(
    const float* __restrict__ x1, const float* __restrict__ x2,
    const float* __restrict__ x3, const float* __restrict__ x4,
    const float* __restrict__ lg1, const float* __restrict__ lg2,
    const float* __restrict__ lg3, const float* __restrict__ lg4,
    const float* __restrict__ W1, const float* __restrict__ bb1,
    const float* __restrict__ W2, const float* __restrict__ bb2,
    const float* __restrict__ W3, const float* __restrict__ bb3,
    const float* __restrict__ W4, const float* __restrict__ bb4,
    float* __restrict__ out_nc, float* __restrict__ s_out)
{
    const int b    = blockIdx.x;
    const int tid  = threadIdx.x;
    const int wave = tid >> 6;
    const int lane = tid & 63;

    __shared__ float conf_s[4];
    __shared__ float part_s[4][4];  // [wave][group]

    // ---- phase 1: confidence per head; wave w handles logits_{w+1} ----
    {
        const float* lg = (wave == 0) ? lg1 : (wave == 1) ? lg2 : (wave == 2) ? lg3 : lg4;
        float v = (lane < NCLS) ? lg[b * NCLS + lane] : -INFINITY;
        float m = wave_max(v);
        float e = (lane < NCLS) ? __expf(v - m) : 0.0f;
        float S = wave_sum(e);
        float p = e / S;
        float t = (lane < NCLS) ? p * __logf(p + 1e-8f) : 0.0f;
        float ent = -wave_sum(t);
        // max_p = exp(0)/S = 1/S ; norm_ent = ent/ln(62), ln(62)=4.1271343580
        float conf = (1.0f / S) * (1.0f - ent * 0.242298797f);
        if (lane == 0) conf_s[wave] = conf;
    }
    __syncthreads();

    // ---- phase 2: four dot products (float4 vectorized, whole block each) ----
    const int fan4[4] = {1536, 2304, 2560, 1536};  // fan_in/4 per group
    const float4* xv[4] = {(const float4*)x1, (const float4*)x2,
                           (const float4*)x3, (const float4*)x4};
    const float4* wv[4] = {(const float4*)W1, (const float4*)W2,
                           (const float4*)W3, (const float4*)W4};
#pragma unroll
    for (int i = 0; i < 4; ++i) {
        const float4* xp = xv[i] + (size_t)b * fan4[i];
        const float4* wp = wv[i];
        float a = 0.0f;
        for (int j = tid; j < fan4[i]; j += 256) {
            float4 xx = xp[j];
            float4 ww = wp[j];
            a += xx.x * ww.x + xx.y * ww.y + xx.z * ww.z + xx.w * ww.w;
        }
        a = wave_sum(a);
        if (lane == 0) part_s[wave][i] = a;
    }
    __syncthreads();

    if (tid < 4) {
        const int i = tid;
        float dot = part_s[0][i] + part_s[1][i] + part_s[2][i] + part_s[3][i];
        float bias = (i == 0) ? bb1[0] : (i == 1) ? bb2[0] : (i == 2) ? bb3[0] : bb4[0];
        float u = 1.0f / (1.0f + __expf(-(dot + bias)));
        // softmax over the 4 confidences
        float c0 = conf_s[0], c1 = conf_s[1], c2 = conf_s[2], c3 = conf_s[3];
        float m4 = fmaxf(fmaxf(c0, c1), fmaxf(c2, c3));
        float e0 = __expf(c0 - m4), e1 = __expf(c1 - m4);
        float e2 = __expf(c2 - m4), e3 = __expf(c3 - m4);
        float S4 = e0 + e1 + e2 + e3;
        float ei = (i == 0) ? e0 : (i == 1) ? e1 : (i == 2) ? e2 : e3;
        float nc = ei / S4;
        out_nc[i * BATCH + b] = nc;       // outputs 0..3, each (B,1)
        s_out[b * 4 + i] = u * nc;        // scale for trans kernel
    }
}

// row r of trans -> (group, channel-within-group): inverse of _GROUPS
__device__ const unsigned char GRP_TBL[62] = {
    0,0,0,0,0, 1, 0,0,0,0,0,0,0,           // 0-12
    1,1,1,                                  // 13-15
    2,2,2,2,2,                              // 16-20
    1,1,1,1,                                // 21-24
    2,2,2,2,2,                              // 25-29
    1,1,1,1,                                // 30-33
    2,2,2,2,2,                              // 34-38
    1,1,1,1,                                // 39-42
    2,2,2,2,2,                              // 43-47
    1,1,                                    // 48-49
    3,3,3,3,3,3,3,3,3,3,3,3                 // 50-61
};
__device__ const unsigned char CHAN_TBL[62] = {
    1,0,2,3,4, 0, 5,6,7,8,9,10,11,
    1,2,3,
    0,1,2,3,4,
    4,5,6,7,
    5,6,7,8,9,
    8,9,10,11,
    10,11,12,13,14,
    12,13,14,15,
    15,16,17,18,19,
    16,17,
    0,1,2,3,4,5,6,7,8,9,10,11
};

// Kernel B: trans[b,r,:] = (x_grp[b,ch,:] + g[b,r,:]) * s[b,grp]
__global__ __launch_bounds__(256) void trans_kernel(
    const float4* __restrict__ x1, const float4* __restrict__ x2,
    const float4* __restrict__ x3, const float4* __restrict__ x4,
    const float4* __restrict__ g, const float* __restrict__ s,
    float4* __restrict__ out)
{
    int idx = blockIdx.x * 256 + threadIdx.x;   // one float4 per thread
    int d4  = idx & 127;                        // 512/4 = 128 float4 per row
    int row = idx >> 7;                         // b*62 + r
    int b   = row / 62;
    int r   = row - b * 62;
    int grp = GRP_TBL[r];
    int ch  = CHAN_TBL[r];
    const float4* xp;
    int chN;
    if (grp == 0)      { xp = x1; chN = 12; }
    else if (grp == 1) { xp = x2; chN = 18; }
    else if (grp == 2) { xp = x3; chN = 20; }
    else               { xp = x4; chN = 12; }
    float sc = s[b * 4 + grp];
    float4 xx = xp[((size_t)b * chN + ch) * 128 + d4];
    float4 gg = g[(size_t)row * 128 + d4];
    float4 o;
    o.x = (xx.x + gg.x) * sc;
    o.y = (xx.y + gg.y) * sc;
    o.z = (xx.z + gg.z) * sc;
    o.w = (xx.w + gg.w) * sc;
    out[(size_t)row * 128 + d4] = o;
}

extern "C" void kernel_launch(void* const* d_in, const int* in_sizes, int n_in,
                              void* d_out, int out_size, void* d_ws, size_t ws_size,
                              hipStream_t stream) {
    const float* x1  = (const float*)d_in[0];
    const float* x2  = (const float*)d_in[1];
    const float* x3  = (const float*)d_in[2];
    const float* x4  = (const float*)d_in[3];
    const float* g   = (const float*)d_in[4];
    const float* lg1 = (const float*)d_in[5];
    const float* lg2 = (const float*)d_in[6];
    const float* lg3 = (const float*)d_in[7];
    const float* lg4 = (const float*)d_in[8];
    const float* W1  = (const float*)d_in[9];
    const float* b1  = (const float*)d_in[10];
    const float* W2  = (const float*)d_in[11];
    const float* b2  = (const float*)d_in[12];
    const float* W3  = (const float*)d_in[13];
    const float* b3  = (const float*)d_in[14];
    const float* W4  = (const float*)d_in[15];
    const float* b4  = (const float*)d_in[16];

    float* out  = (float*)d_out;
    float* s_ws = (float*)d_ws;   // 2048*4 floats of scratch

    head_kernel<<<BATCH, 256, 0, stream>>>(
        x1, x2, x3, x4, lg1, lg2, lg3, lg4,
        W1, b1, W2, b2, W3, b3, W4, b4,
        out, s_ws);

    // trans output starts after the four (B,1) outputs: offset 4*2048 floats
    int total_f4 = BATCH * 62 * 128;            // 16,252,928
    trans_kernel<<<total_f4 / 256, 256, 0, stream>>>(
        (const float4*)x1, (const float4*)x2, (const float4*)x3, (const float4*)x4,
        (const float4*)g, s_ws, (float4*)(out + 4 * BATCH));
}